// Round 10
// baseline (24.937 us; speedup 1.0000x reference)
//
#include <hip/hip_runtime.h>

// Diagonal SSM as truncated depthwise FIR conv — FUSED single kernel.
// |A| = exp(A_log) <= e^-1 => 8 taps, tail error ~4e-4 << 0.118 threshold.
//
// R9 -> R10: A-side vectorization was a no-op => the residual ~9us over B's
// ~10.5us memory floor is two-dispatch overhead (tiny-grid A + gap + drain).
// Fuse: each thread recomputes the 8 taps for its own 4 m-columns via the
// p *= A recurrence (A = -exp(A_log) < 0 folds the (-1)^tau sign for free).
// ~1150 scalar VALU ops/thread ~ 3us chip-wide, hidden under the 13us
// memory window by 16 waves/CU TLP. Tap-phase regs (~90, s-chunked via
// #pragma unroll 1 to stop load-hoisting) are disjoint from conv-phase
// (~102), peak ~110 < 128 cap at launch_bounds(256,4) -> no spill.

#define M_DIM 1024
#define S_DIM 16
#define L_DIM 4096
#define B_DIM 2
#define TAPS  8    // FIR length
#define WT    8    // outputs (t) per thread
#define BLOCK 256  // thread owns 4 m -> block covers M=1024

typedef float f32x4 __attribute__((ext_vector_type(4)));

__global__ __launch_bounds__(BLOCK, 4)
void ssm_fused_kernel(const float* __restrict__ x,
                      const float* __restrict__ A_log,
                      const float* __restrict__ Bmat,
                      const float* __restrict__ Cmat,
                      const float* __restrict__ Dvec,
                      float* __restrict__ y) {
    const int tid = threadIdx.x;
    const int bid = blockIdx.x;

    // 1024 blocks: bits {xcd:3, b:1, rest:6}. Each (xcd,b) owns the
    // contiguous c-strip [xcd*64, xcd*64+64) -> halo rows stay in that
    // XCD's L2 under %8 round-robin dispatch.
    const int xcd  = bid & 7;
    const int b    = (bid >> 3) & 1;
    const int rest = bid >> 4;              // 0..63
    const int c    = xcd * 64 + rest;       // 0..511
    const int t0   = c * WT;
    const int m0   = tid * 4;               // this thread's 4 channels

    // ---- Phase 1: taps. K[tau] = sum_s C[m,s]B[s,m] * A^tau, A = -exp(.) ----
    f32x4 K[TAPS];
    #pragma unroll
    for (int tau = 0; tau < TAPS; ++tau) K[tau] = (f32x4)(0.0f);

    #pragma unroll 1   // runtime loop: keeps per-chunk loads from hoisting
    for (int sc = 0; sc < 4; ++sc) {
        const f32x4 crow0 = *(const f32x4*)(Cmat + (size_t)(m0 + 0) * S_DIM + sc * 4);
        const f32x4 crow1 = *(const f32x4*)(Cmat + (size_t)(m0 + 1) * S_DIM + sc * 4);
        const f32x4 crow2 = *(const f32x4*)(Cmat + (size_t)(m0 + 2) * S_DIM + sc * 4);
        const f32x4 crow3 = *(const f32x4*)(Cmat + (size_t)(m0 + 3) * S_DIM + sc * 4);
        f32x4 br[4], ar[4];
        #pragma unroll
        for (int i = 0; i < 4; ++i) {
            br[i] = *(const f32x4*)(Bmat  + (size_t)(sc * 4 + i) * M_DIM + m0);
            ar[i] = *(const f32x4*)(A_log + (size_t)(sc * 4 + i) * M_DIM + m0);
        }
        #pragma unroll
        for (int i = 0; i < 4; ++i) {
            f32x4 w;
            w.x = crow0[i] * br[i].x;
            w.y = crow1[i] * br[i].y;
            w.z = crow2[i] * br[i].z;
            w.w = crow3[i] * br[i].w;
            f32x4 A;
            A.x = -__expf(ar[i].x); A.y = -__expf(ar[i].y);
            A.z = -__expf(ar[i].z); A.w = -__expf(ar[i].w);
            f32x4 p = w;
            K[0] += p;
            #pragma unroll
            for (int tau = 1; tau < TAPS; ++tau) { p *= A; K[tau] += p; }
        }
    }
    K[0] += *(const f32x4*)(Dvec + m0);   // D folded into tap 0

    // ---- Phase 2: truncated causal conv, flat register window ----
    const f32x4* x4 = (const f32x4*)x + (size_t)b * L_DIM * (M_DIM / 4) + tid;

    f32x4 xw[WT + TAPS - 1];   // rows t0-7 .. t0+7, 15 coalesced 16B loads
    #pragma unroll
    for (int j = 0; j < WT + TAPS - 1; ++j) {
        int t = t0 - (TAPS - 1) + j;
        if (t >= 0) {
            xw[j] = x4[(size_t)t * (M_DIM / 4)];
        } else {
            xw[j] = (f32x4)(0.0f);
        }
    }

    f32x4* y4 = (f32x4*)y + ((size_t)b * L_DIM + t0) * (M_DIM / 4) + tid;
    #pragma unroll
    for (int i = 0; i < WT; ++i) {
        f32x4 a = (f32x4)(0.0f);
        #pragma unroll
        for (int tau = 0; tau < TAPS; ++tau)
            a += K[tau] * xw[TAPS - 1 + i - tau];
        __builtin_nontemporal_store(a, &y4[(size_t)i * (M_DIM / 4)]);
    }
}

extern "C" void kernel_launch(void* const* d_in, const int* in_sizes, int n_in,
                              void* d_out, int out_size, void* d_ws, size_t ws_size,
                              hipStream_t stream) {
    const float* x     = (const float*)d_in[0];
    const float* A_log = (const float*)d_in[1];
    const float* Bmat  = (const float*)d_in[2];
    const float* Cmat  = (const float*)d_in[3];
    const float* Dvec  = (const float*)d_in[4];
    float* y = (float*)d_out;

    // 2 b x 512 c = 1024 blocks, each covering all 1024 m
    ssm_fused_kernel<<<dim3(B_DIM * (L_DIM / WT)), BLOCK, 0, stream>>>(
        x, A_log, Bmat, Cmat, Dvec, y);
}

// Round 11
// 21.373 us; speedup vs baseline: 1.1668x; 1.1668x over previous
//
#include <hip/hip_runtime.h>

// Diagonal SSM as truncated depthwise FIR conv, two-kernel version.
// |A| = exp(A_log) <= e^-1 => 8 taps gives tail error ~4e-4 << 0.118 thr.
//
// R10 -> R11: fused version regressed +5.1us = per-SIMD serial tap phase
// (4 waves x 1600 ops x 2cy ~ 5.3us) -> keep the two-kernel split.
// R1's clean profile of the conv kernel showed VALUBusy 32% / Occ 37% /
// HBM 19% = latency-bound. R9 was pinned at 4 waves/SIMD (VGPR ~100 + grid
// 1024 = 4 blk/CU). This round: f32x2 lanes, WT=8, TAPS=8 -> arrays 46
// VGPR (~58 total), launch_bounds(256,7) (cap 73, no-spill margin),
// grid 2048 = 8 blk/CU -> 7 waves/SIMD resident, +75% TLP.

#define M_DIM 1024
#define S_DIM 16
#define L_DIM 4096
#define B_DIM 2
#define TAPS  8    // FIR length
#define WT    8    // outputs (t) per thread
#define BLOCK 256  // thread owns 1 f32x2 -> block covers 512 m (half)

typedef float f32x2 __attribute__((ext_vector_type(2)));
typedef float f32x4 __attribute__((ext_vector_type(4)));

// ---- Kernel A: K[tau][m] = (-1)^tau sum_s C[m,s]B[s,m] exp(tau*A_log[s,m]),
//      D[m] folded into tau=0. Grid (TAPS, M/BLOCK) = 32 blocks. ----
__global__ __launch_bounds__(BLOCK)
void ssm_taps_kernel(const float* __restrict__ A_log,
                     const float* __restrict__ Bmat,
                     const float* __restrict__ Cmat,
                     const float* __restrict__ Dvec,
                     float* __restrict__ Kout) {
    const int tau = blockIdx.x;
    const int m   = blockIdx.y * BLOCK + threadIdx.x;
    const float ft = (float)tau;

    const f32x4* c4 = (const f32x4*)(Cmat + (size_t)m * S_DIM);
    f32x4 c0 = c4[0], c1 = c4[1], c2 = c4[2], c3 = c4[3];
    float cr[S_DIM] = {c0.x, c0.y, c0.z, c0.w, c1.x, c1.y, c1.z, c1.w,
                       c2.x, c2.y, c2.z, c2.w, c3.x, c3.y, c3.z, c3.w};

    float acc = 0.0f;
    #pragma unroll
    for (int s = 0; s < S_DIM; ++s) {
        float w = cr[s] * Bmat[s * M_DIM + m];
        acc = fmaf(w, __expf(ft * A_log[s * M_DIM + m]), acc);
    }
    float k = (tau & 1) ? -acc : acc;
    if (tau == 0) k += Dvec[m];
    Kout[tau * M_DIM + m] = k;
}

// ---- Kernel B: truncated causal conv, f32x2 lanes, high occupancy ----
__global__ __launch_bounds__(BLOCK, 7)
void ssm_fir_kernel(const float* __restrict__ x,
                    const float* __restrict__ Kin,
                    float* __restrict__ y) {
    const int tid = threadIdx.x;
    const int bid = blockIdx.x;

    // 2048 blocks: bits {xcd:3, b:1, mhalf:1, rest:6}. Each (xcd,b,mhalf)
    // owns the contiguous c-strip [xcd*64, xcd*64+64) -> halo rows stay on
    // that XCD's L2 under %8 round-robin dispatch.
    const int xcd   = bid & 7;
    const int b     = (bid >> 3) & 1;
    const int mhalf = (bid >> 4) & 1;
    const int rest  = bid >> 5;             // 0..63
    const int c     = xcd * 64 + rest;      // 0..511

    const int t0 = c * WT;
    const int f2 = mhalf * 256 + tid;       // f32x2 column, 0..511

    const f32x2* x2 = (const f32x2*)x + (size_t)b * L_DIM * (M_DIM / 2) + f2;
    const f32x2* K2 = (const f32x2*)Kin + f2;

    // K taps: 8 f32x2 registers (L2-resident 32 KB table, coalesced)
    f32x2 K[TAPS];
    #pragma unroll
    for (int tau = 0; tau < TAPS; ++tau)
        K[tau] = K2[(size_t)tau * (M_DIM / 2)];

    // x window rows t0-7 .. t0+7: 15 independent coalesced loads
    f32x2 xw[WT + TAPS - 1];
    #pragma unroll
    for (int j = 0; j < WT + TAPS - 1; ++j) {
        int t = t0 - (TAPS - 1) + j;
        if (t >= 0) {
            xw[j] = x2[(size_t)t * (M_DIM / 2)];
        } else {
            xw[j] = (f32x2)(0.0f);
        }
    }

    f32x2* y2 = (f32x2*)y + ((size_t)b * L_DIM + t0) * (M_DIM / 2) + f2;
    #pragma unroll
    for (int i = 0; i < WT; ++i) {
        f32x2 a = (f32x2)(0.0f);
        #pragma unroll
        for (int tau = 0; tau < TAPS; ++tau)
            a += K[tau] * xw[TAPS - 1 + i - tau];
        __builtin_nontemporal_store(a, &y2[(size_t)i * (M_DIM / 2)]);
    }
}

extern "C" void kernel_launch(void* const* d_in, const int* in_sizes, int n_in,
                              void* d_out, int out_size, void* d_ws, size_t ws_size,
                              hipStream_t stream) {
    const float* x     = (const float*)d_in[0];
    const float* A_log = (const float*)d_in[1];
    const float* Bmat  = (const float*)d_in[2];
    const float* Cmat  = (const float*)d_in[3];
    const float* Dvec  = (const float*)d_in[4];
    float* y = (float*)d_out;
    float* Kws = (float*)d_ws;  // TAPS * M_DIM floats = 32 KB

    ssm_taps_kernel<<<dim3(TAPS, M_DIM / BLOCK), BLOCK, 0, stream>>>(
        A_log, Bmat, Cmat, Dvec, Kws);
    // 2 b x 2 mhalf x 512 c = 2048 blocks
    ssm_fir_kernel<<<dim3(B_DIM * 2 * (L_DIM / WT)), BLOCK, 0, stream>>>(
        x, Kws, y);
}

// Round 12
// 17.564 us; speedup vs baseline: 1.4198x; 1.2169x over previous
//
#include <hip/hip_runtime.h>

// Diagonal SSM as truncated depthwise FIR conv — fused, cooperative taps.
// |A| = exp(A_log) <= e^-1 => 8 taps, tail error ~4e-4 << 0.118 threshold.
//
// R11 -> R12: two-kernel floor = B(~13) + A(~2) + 2 graph nodes(~4).
// R10's fused regression was tap redundancy (each thread: 4m x 16s chains
// = ~1024 VALU => ~3.4us SIMD prefix). Fix: BLOCK=1024 covers 32t x all
// 1024m; tap phase = 1 thread per m (~250 VALU) -> K to 32KB LDS ->
// barrier -> conv phase remaps to (t-quarter, f32x4 column) and runs the
// proven R8 conv (16B lanes, WT=8, nt stores). 4x less tap work than R10,
// one dispatch, no kernel A.

#define M_DIM 1024
#define S_DIM 16
#define L_DIM 4096
#define B_DIM 2
#define TAPS  8    // FIR length
#define WT    8    // outputs (t) per thread
#define WTB   32   // t per block (4 quarters)
#define BLOCK 1024

typedef float f32x4 __attribute__((ext_vector_type(4)));

__global__ __launch_bounds__(BLOCK, 4)
void ssm_fused_kernel(const float* __restrict__ x,
                      const float* __restrict__ A_log,
                      const float* __restrict__ Bmat,
                      const float* __restrict__ Cmat,
                      const float* __restrict__ Dvec,
                      float* __restrict__ y) {
    __shared__ float Klds[TAPS][M_DIM];   // 32 KB

    const int tid = threadIdx.x;
    const int bid = blockIdx.x;

    // 256 blocks: bits {xcd:3, b:1, rest:4}. Each (xcd,b) owns contiguous
    // c32-strip [xcd*16, xcd*16+16) -> halo rows stay on one XCD's L2.
    const int xcd  = bid & 7;
    const int b    = (bid >> 3) & 1;
    const int rest = bid >> 4;                // 0..15
    const int c32  = xcd * 16 + rest;         // 0..127

    // ---- Phase 1: cooperative taps, one thread per m ----
    {
        const int m = tid;
        const f32x4* c4 = (const f32x4*)(Cmat + (size_t)m * S_DIM);
        f32x4 c0 = c4[0], c1 = c4[1], c2 = c4[2], c3 = c4[3];
        float cr[S_DIM] = {c0.x, c0.y, c0.z, c0.w, c1.x, c1.y, c1.z, c1.w,
                           c2.x, c2.y, c2.z, c2.w, c3.x, c3.y, c3.z, c3.w};
        float K[TAPS];
        #pragma unroll
        for (int tau = 0; tau < TAPS; ++tau) K[tau] = 0.0f;
        #pragma unroll
        for (int s = 0; s < S_DIM; ++s) {
            float bb = Bmat[s * M_DIM + m];
            float al = A_log[s * M_DIM + m];
            float w  = cr[s] * bb;
            float A  = -__expf(al);           // negative: folds (-1)^tau
            float p  = w;
            K[0] += p;
            #pragma unroll
            for (int tau = 1; tau < TAPS; ++tau) { p *= A; K[tau] += p; }
        }
        K[0] += Dvec[m];                      // D folded into tap 0
        #pragma unroll
        for (int tau = 0; tau < TAPS; ++tau) Klds[tau][m] = K[tau];
    }
    __syncthreads();

    // ---- Phase 2: conv. Remap: tq = t-quarter, m4 = f32x4 column ----
    const int tq = tid >> 8;                  // 0..3
    const int m4 = tid & 255;                 // 0..255
    const int t0 = c32 * WTB + tq * WT;

    f32x4 K[TAPS];
    #pragma unroll
    for (int tau = 0; tau < TAPS; ++tau)
        K[tau] = *(const f32x4*)&Klds[tau][m4 * 4];

    const f32x4* x4 = (const f32x4*)x + (size_t)b * L_DIM * (M_DIM / 4) + m4;

    f32x4 xw[WT + TAPS - 1];   // rows t0-7 .. t0+7, 15 coalesced 16B loads
    #pragma unroll
    for (int j = 0; j < WT + TAPS - 1; ++j) {
        int t = t0 - (TAPS - 1) + j;
        if (t >= 0) {
            xw[j] = x4[(size_t)t * (M_DIM / 4)];
        } else {
            xw[j] = (f32x4)(0.0f);
        }
    }

    f32x4* y4 = (f32x4*)y + ((size_t)b * L_DIM + t0) * (M_DIM / 4) + m4;
    #pragma unroll
    for (int i = 0; i < WT; ++i) {
        f32x4 a = (f32x4)(0.0f);
        #pragma unroll
        for (int tau = 0; tau < TAPS; ++tau)
            a += K[tau] * xw[TAPS - 1 + i - tau];
        __builtin_nontemporal_store(a, &y4[(size_t)i * (M_DIM / 4)]);
    }
}

extern "C" void kernel_launch(void* const* d_in, const int* in_sizes, int n_in,
                              void* d_out, int out_size, void* d_ws, size_t ws_size,
                              hipStream_t stream) {
    const float* x     = (const float*)d_in[0];
    const float* A_log = (const float*)d_in[1];
    const float* Bmat  = (const float*)d_in[2];
    const float* Cmat  = (const float*)d_in[3];
    const float* Dvec  = (const float*)d_in[4];
    float* y = (float*)d_out;

    // 2 b x 128 c32-chunks = 256 blocks (exactly 1 per CU)
    ssm_fused_kernel<<<dim3(B_DIM * (L_DIM / WTB)), BLOCK, 0, stream>>>(
        x, A_log, Bmat, Cmat, Dvec, y);
}

// Round 13
// 15.900 us; speedup vs baseline: 1.5684x; 1.1046x over previous
//
#include <hip/hip_runtime.h>

// Diagonal SSM as truncated depthwise FIR conv — fused, cooperative taps.
// |A| = exp(A_log) <= e^-1 => 8 taps, tail error ~4e-4 << 0.118 threshold.
//
// R12 -> R13: R12 (17.6us) = conv ~13 + tap prefix ~1.5 + launch ~2; at
// 1 block/CU the memory pipe idles during taps + barrier. This round:
// BLOCK=512 over (mhalf, 32t), grid 512 = 2 blocks/CU, 8 waves/SIMD —
// block A's conv streams while block B computes taps. xw loads issued
// BEFORE the tap phase (independent; __syncthreads' vmcnt(0) drains them
// under the ~500cy tap compute). Peak VGPR ~110 < 128 cap -> no spill.

#define M_DIM 1024
#define S_DIM 16
#define L_DIM 4096
#define B_DIM 2
#define TAPS  8    // FIR length
#define WT    8    // outputs (t) per thread
#define WTB   32   // t per block (4 quarters)
#define BLOCK 512  // covers 512 m (half of M) x 32 t

typedef float f32x4 __attribute__((ext_vector_type(4)));

__global__ __launch_bounds__(BLOCK, 4)
void ssm_fused_kernel(const float* __restrict__ x,
                      const float* __restrict__ A_log,
                      const float* __restrict__ Bmat,
                      const float* __restrict__ Cmat,
                      const float* __restrict__ Dvec,
                      float* __restrict__ y) {
    __shared__ float Klds[TAPS][BLOCK];   // 16 KB

    const int tid = threadIdx.x;
    const int bid = blockIdx.x;

    // 512 blocks: bits {xcd:3, b:1, mhalf:1, rest:4}. Each (xcd,b,mhalf)
    // owns contiguous c32-strip [xcd*16, xcd*16+16) -> halo on one XCD's L2.
    const int xcd   = bid & 7;
    const int b     = (bid >> 3) & 1;
    const int mhalf = (bid >> 4) & 1;
    const int rest  = bid >> 5;               // 0..15
    const int c32   = xcd * 16 + rest;        // 0..127

    // ---- Conv-phase mapping (needed now to issue x loads early) ----
    const int tq = tid >> 7;                  // 0..3  (t-quarter)
    const int m4 = tid & 127;                 // 0..127 (f32x4 column in half)
    const int t0 = c32 * WTB + tq * WT;
    const int col4 = mhalf * (M_DIM / 8) + m4;  // global f32x4 column

    const f32x4* x4 = (const f32x4*)x + (size_t)b * L_DIM * (M_DIM / 4) + col4;

    // Issue the 15 window loads BEFORE the tap phase; they complete under it.
    f32x4 xw[WT + TAPS - 1];   // rows t0-7 .. t0+7
    #pragma unroll
    for (int j = 0; j < WT + TAPS - 1; ++j) {
        int t = t0 - (TAPS - 1) + j;
        if (t >= 0) {
            xw[j] = x4[(size_t)t * (M_DIM / 4)];
        } else {
            xw[j] = (f32x4)(0.0f);
        }
    }

    // ---- Phase 1: cooperative taps, one thread per m in this half ----
    {
        const int m = mhalf * BLOCK + tid;    // global channel
        const f32x4* c4 = (const f32x4*)(Cmat + (size_t)m * S_DIM);
        f32x4 c0 = c4[0], c1 = c4[1], c2 = c4[2], c3 = c4[3];
        float cr[S_DIM] = {c0.x, c0.y, c0.z, c0.w, c1.x, c1.y, c1.z, c1.w,
                           c2.x, c2.y, c2.z, c2.w, c3.x, c3.y, c3.z, c3.w};
        float K[TAPS];
        #pragma unroll
        for (int tau = 0; tau < TAPS; ++tau) K[tau] = 0.0f;
        #pragma unroll
        for (int s = 0; s < S_DIM; ++s) {
            float bb = Bmat[s * M_DIM + m];
            float al = A_log[s * M_DIM + m];
            float w  = cr[s] * bb;
            float A  = -__expf(al);           // negative: folds (-1)^tau
            float p  = w;
            K[0] += p;
            #pragma unroll
            for (int tau = 1; tau < TAPS; ++tau) { p *= A; K[tau] += p; }
        }
        K[0] += Dvec[m];                      // D folded into tap 0
        #pragma unroll
        for (int tau = 0; tau < TAPS; ++tau) Klds[tau][tid] = K[tau];
    }
    __syncthreads();

    // ---- Phase 2: conv ----
    f32x4 K[TAPS];
    #pragma unroll
    for (int tau = 0; tau < TAPS; ++tau)
        K[tau] = *(const f32x4*)&Klds[tau][m4 * 4];

    f32x4* y4 = (f32x4*)y + ((size_t)b * L_DIM + t0) * (M_DIM / 4) + col4;
    #pragma unroll
    for (int i = 0; i < WT; ++i) {
        f32x4 a = (f32x4)(0.0f);
        #pragma unroll
        for (int tau = 0; tau < TAPS; ++tau)
            a += K[tau] * xw[TAPS - 1 + i - tau];
        __builtin_nontemporal_store(a, &y4[(size_t)i * (M_DIM / 4)]);
    }
}

extern "C" void kernel_launch(void* const* d_in, const int* in_sizes, int n_in,
                              void* d_out, int out_size, void* d_ws, size_t ws_size,
                              hipStream_t stream) {
    const float* x     = (const float*)d_in[0];
    const float* A_log = (const float*)d_in[1];
    const float* Bmat  = (const float*)d_in[2];
    const float* Cmat  = (const float*)d_in[3];
    const float* Dvec  = (const float*)d_in[4];
    float* y = (float*)d_out;

    // 2 b x 2 mhalf x 128 c32 = 512 blocks (2 per CU)
    ssm_fused_kernel<<<dim3(B_DIM * 2 * (L_DIM / WTB)), BLOCK, 0, stream>>>(
        x, A_log, Bmat, Cmat, Dvec, y);
}

// Round 14
// 15.653 us; speedup vs baseline: 1.5931x; 1.0158x over previous
//
#include <hip/hip_runtime.h>

// Diagonal SSM as truncated depthwise FIR conv — fused, cooperative taps.
// |A| = exp(A_log) <= e^-1 => 8 taps, tail error ~4e-4 << 0.118 threshold.
//
// R13 -> R14: single variable — barrier-group granularity. BLOCK 512->256
// (4 independent blocks/CU instead of 2; same 16 waves/CU, same total tap
// work). While one block sits in tap-VALU or barrier drain, three others
// stream VMEM. R12->R13 (1->2 blocks/CU) gained 1.7us on this mechanism.
// Conv structure (f32x4 lanes, WT=8, nt stores, early xw issue,
// XCD-chunked c-strips) is byte-identical to R13.

#define M_DIM 1024
#define S_DIM 16
#define L_DIM 4096
#define B_DIM 2
#define TAPS  8    // FIR length
#define WT    8    // outputs (t) per thread
#define WTB   32   // t per block (4 quarters)
#define BLOCK 256  // covers 256 m (quarter of M) x 32 t

typedef float f32x4 __attribute__((ext_vector_type(4)));

__global__ __launch_bounds__(BLOCK, 4)
void ssm_fused_kernel(const float* __restrict__ x,
                      const float* __restrict__ A_log,
                      const float* __restrict__ Bmat,
                      const float* __restrict__ Cmat,
                      const float* __restrict__ Dvec,
                      float* __restrict__ y) {
    __shared__ float Klds[TAPS][BLOCK];   // 8 KB

    const int tid = threadIdx.x;
    const int bid = blockIdx.x;

    // 1024 blocks: bits {xcd:3, b:1, mq:2, rest:4}. Each (xcd,b,mq) owns
    // the contiguous c32-strip [xcd*16, xcd*16+16) -> halo on one XCD's L2.
    const int xcd  = bid & 7;
    const int b    = (bid >> 3) & 1;
    const int mq   = (bid >> 4) & 3;          // m-quarter
    const int rest = bid >> 6;                // 0..15
    const int c32  = xcd * 16 + rest;         // 0..127

    // ---- Conv-phase mapping (needed now to issue x loads early) ----
    const int tq = tid >> 6;                  // 0..3  (t-quarter)
    const int m4 = tid & 63;                  // 0..63 (f32x4 col in quarter)
    const int t0 = c32 * WTB + tq * WT;
    const int col4 = mq * (M_DIM / 16) + m4;  // global f32x4 column

    const f32x4* x4 = (const f32x4*)x + (size_t)b * L_DIM * (M_DIM / 4) + col4;

    // Issue the 15 window loads BEFORE the tap phase; they complete under it.
    f32x4 xw[WT + TAPS - 1];   // rows t0-7 .. t0+7
    #pragma unroll
    for (int j = 0; j < WT + TAPS - 1; ++j) {
        int t = t0 - (TAPS - 1) + j;
        if (t >= 0) {
            xw[j] = x4[(size_t)t * (M_DIM / 4)];
        } else {
            xw[j] = (f32x4)(0.0f);
        }
    }

    // ---- Phase 1: cooperative taps, one thread per m in this quarter ----
    {
        const int m = mq * BLOCK + tid;       // global channel
        const f32x4* c4 = (const f32x4*)(Cmat + (size_t)m * S_DIM);
        f32x4 c0 = c4[0], c1 = c4[1], c2 = c4[2], c3 = c4[3];
        float cr[S_DIM] = {c0.x, c0.y, c0.z, c0.w, c1.x, c1.y, c1.z, c1.w,
                           c2.x, c2.y, c2.z, c2.w, c3.x, c3.y, c3.z, c3.w};
        float K[TAPS];
        #pragma unroll
        for (int tau = 0; tau < TAPS; ++tau) K[tau] = 0.0f;
        #pragma unroll
        for (int s = 0; s < S_DIM; ++s) {
            float bb = Bmat[s * M_DIM + m];
            float al = A_log[s * M_DIM + m];
            float w  = cr[s] * bb;
            float A  = -__expf(al);           // negative: folds (-1)^tau
            float p  = w;
            K[0] += p;
            #pragma unroll
            for (int tau = 1; tau < TAPS; ++tau) { p *= A; K[tau] += p; }
        }
        K[0] += Dvec[m];                      // D folded into tap 0
        #pragma unroll
        for (int tau = 0; tau < TAPS; ++tau) Klds[tau][tid] = K[tau];
    }
    __syncthreads();

    // ---- Phase 2: conv ----
    f32x4 K[TAPS];
    #pragma unroll
    for (int tau = 0; tau < TAPS; ++tau)
        K[tau] = *(const f32x4*)&Klds[tau][m4 * 4];

    f32x4* y4 = (f32x4*)y + ((size_t)b * L_DIM + t0) * (M_DIM / 4) + col4;
    #pragma unroll
    for (int i = 0; i < WT; ++i) {
        f32x4 a = (f32x4)(0.0f);
        #pragma unroll
        for (int tau = 0; tau < TAPS; ++tau)
            a += K[tau] * xw[TAPS - 1 + i - tau];
        __builtin_nontemporal_store(a, &y4[(size_t)i * (M_DIM / 4)]);
    }
}

extern "C" void kernel_launch(void* const* d_in, const int* in_sizes, int n_in,
                              void* d_out, int out_size, void* d_ws, size_t ws_size,
                              hipStream_t stream) {
    const float* x     = (const float*)d_in[0];
    const float* A_log = (const float*)d_in[1];
    const float* Bmat  = (const float*)d_in[2];
    const float* Cmat  = (const float*)d_in[3];
    const float* Dvec  = (const float*)d_in[4];
    float* y = (float*)d_out;

    // 2 b x 4 mq x 128 c32 = 1024 blocks (4 per CU)
    ssm_fused_kernel<<<dim3(B_DIM * 4 * (L_DIM / WTB)), BLOCK, 0, stream>>>(
        x, A_log, Bmat, Cmat, Dvec, y);
}